// Round 3
// baseline (813.306 us; speedup 1.0000x reference)
//
#include <hip/hip_runtime.h>

#define Rn 64
#define Hn 10
#define Fn 5

__device__ __forceinline__ float fsigmoid(float x) {
    return __builtin_amdgcn_rcpf(1.0f + __expf(-x));
}
__device__ __forceinline__ float ftanh(float x) {
    return 1.0f - 2.0f * __builtin_amdgcn_rcpf(__expf(2.0f * x) + 1.0f);
}

// 128 threads = 2 waves per block; block owns 64 batches (batch = lane).
// wave 0 computes LSTM rows 0-4, wave 1 rows 5-9 -> 2048 waves total
// (2/SIMD) and per-wave work halves. Weight addresses are wave-uniform
// (readfirstlane'd row base) -> s_load into SGPRs on the scalar pipe;
// no LDS weight traffic. h_new halves exchanged via LDS, 1 barrier/step.
__global__ __launch_bounds__(128, 2) void seqreader_kernel(
    const float* __restrict__ r_emb,
    const float* __restrict__ feature,
    const float* __restrict__ h0,
    const float* __restrict__ c0,
    const float* __restrict__ W_ih,
    const float* __restrict__ W_hh,
    const float* __restrict__ b_ih,
    const float* __restrict__ b_hh,
    const float* __restrict__ Wr,
    const float* __restrict__ br,
    const float* __restrict__ Wh,
    const float* __restrict__ bh,
    const float* __restrict__ Wfc,
    const float* __restrict__ bfc,
    float* __restrict__ out)
{
    __shared__ float sX[2][64 * 41];   // x tiles, 4 steps each, row stride 41 (odd)
    __shared__ float sHn[2][64][Hn];   // h ping-pong: slot t&1 holds h_t
    __shared__ float sAcc[64];

    const int tid  = threadIdx.x;
    const int lane = tid & 63;
    const int wv   = tid >> 6;
    const int r0   = __builtin_amdgcn_readfirstlane(wv * 5);  // row-half base (SGPR)

    const int b0 = blockIdx.x * 64;
    const int b  = b0 + lane;

    // wave-uniform weight row bases -> scalar loads in the loop
    const float* __restrict__ Wix = W_ih + (0  + r0) * Hn;
    const float* __restrict__ Wfx = W_ih + (10 + r0) * Hn;
    const float* __restrict__ Wgx = W_ih + (20 + r0) * Hn;
    const float* __restrict__ Wox = W_ih + (30 + r0) * Hn;
    const float* __restrict__ Wih = W_hh + (0  + r0) * Hn;
    const float* __restrict__ Wfh = W_hh + (10 + r0) * Hn;
    const float* __restrict__ Wgh = W_hh + (20 + r0) * Hn;
    const float* __restrict__ Woh = W_hh + (30 + r0) * Hn;
    const float* __restrict__ Wrx = Wr + r0 * Hn;
    const float* __restrict__ Whh_ = Wh + r0 * Hn;

    // combined biases into VGPRs once
    float bi[5], bf[5], bg_[5], bo[5], brh[5];
#pragma unroll
    for (int j = 0; j < 5; ++j) {
        bi[j]  = b_ih[0  + r0 + j] + b_hh[0  + r0 + j];
        bf[j]  = b_ih[10 + r0 + j] + b_hh[10 + r0 + j];
        bg_[j] = b_ih[20 + r0 + j] + b_hh[20 + r0 + j];
        bo[j]  = b_ih[30 + r0 + j] + b_hh[30 + r0 + j];
        brh[j] = br[r0 + j] + bh[r0 + j];
    }

    // init c (own rows), publish h0 (own rows) to slot 0
    float c[5];
#pragma unroll
    for (int j = 0; j < 5; ++j) {
        c[j] = c0[b * Hn + r0 + j];
        sHn[0][lane][r0 + j] = h0[b * Hn + r0 + j];
    }

    float acc = 0.0f;
    if (wv == 0) {
        acc = bfc[0];
#pragma unroll
        for (int k = 0; k < Fn; ++k)
            acc = fmaf(feature[b * Fn + k], Wfc[Rn * Hn + k], acc);
    }

    // gather map: tile = 64 batches x 40 floats = 640 float4; 5 per thread
    unsigned off_g[5], off_l[5];
#pragma unroll
    for (int k = 0; k < 5; ++k) {
        int q  = k * 128 + tid;
        int bb = q / 10;
        int e  = q - bb * 10;
        off_g[k] = (unsigned)((bb * (Rn * Hn) + e * 4) * 4);  // bytes
        off_l[k] = (unsigned)(bb * 41 + e * 4);               // dwords
    }
    const char* gb = (const char*)(r_emb + (size_t)b0 * (Rn * Hn));

    // stage tile 0
    {
        float4 s0[5];
#pragma unroll
        for (int k = 0; k < 5; ++k) s0[k] = *(const float4*)(gb + off_g[k]);
#pragma unroll
        for (int k = 0; k < 5; ++k) {
            float* d = &sX[0][off_l[k]];
            d[0] = s0[k].x; d[1] = s0[k].y; d[2] = s0[k].z; d[3] = s0[k].w;
        }
    }
    __syncthreads();

    float4 st[5];
#pragma unroll 1
    for (int t = 0; t < Rn; ++t) {
        const int tt = t & 3;
        const int Tb = (t >> 2) & 1;

        if (tt == 0 && t + 4 < Rn) {
#pragma unroll
            for (int k = 0; k < 5; ++k)
                st[k] = *(const float4*)(gb + off_g[k] + (unsigned)(t / 4 + 1) * 160u);
        }

        // x_t and full h_t
        float x[Hn], hh[Hn];
        const float* xr = &sX[Tb][lane * 41 + tt * Hn];
#pragma unroll
        for (int j = 0; j < Hn; ++j) x[j] = xr[j];
#pragma unroll
        for (int j = 0; j < Hn; ++j) hh[j] = sHn[t & 1][lane][j];

        // own 5 rows of the LSTM cell
        float hn[5];
#pragma unroll
        for (int j = 0; j < 5; ++j) {
            float si = bi[j], sf = bf[j], sg = bg_[j], so = bo[j];
#pragma unroll
            for (int k = 0; k < Hn; ++k) {
                const float xk = x[k], hk = hh[k];
                si = fmaf(Wix[j * Hn + k], xk, si);
                si = fmaf(Wih[j * Hn + k], hk, si);
                sf = fmaf(Wfx[j * Hn + k], xk, sf);
                sf = fmaf(Wfh[j * Hn + k], hk, sf);
                sg = fmaf(Wgx[j * Hn + k], xk, sg);
                sg = fmaf(Wgh[j * Hn + k], hk, sg);
                so = fmaf(Wox[j * Hn + k], xk, so);
                so = fmaf(Woh[j * Hn + k], hk, so);
            }
            const float cn = fsigmoid(sf) * c[j] + fsigmoid(si) * ftanh(sg);
            c[j] = cn;
            hn[j] = fsigmoid(so) * ftanh(cn);
        }

        // publish own h_{t+1} half
#pragma unroll
        for (int j = 0; j < 5; ++j) sHn[(t + 1) & 1][lane][r0 + j] = hn[j];

        // write next x tile (prefetched at tt==0) into the other buffer
        if (tt == 2 && t + 2 < Rn) {
#pragma unroll
            for (int k = 0; k < 5; ++k) {
                float* d = &sX[Tb ^ 1][off_l[k]];
                d[0] = st[k].x; d[1] = st[k].y; d[2] = st[k].z; d[3] = st[k].w;
            }
        }

        __syncthreads();

        // r-gate (needs FULL h_{t+1}) + fused FC accumulation, own rows
        float hf[Hn];
#pragma unroll
        for (int j = 0; j < Hn; ++j) hf[j] = sHn[(t + 1) & 1][lane][j];
#pragma unroll
        for (int j = 0; j < 5; ++j) {
            float s = brh[j];
#pragma unroll
            for (int k = 0; k < Hn; ++k) {
                s = fmaf(Wrx[j * Hn + k], x[k], s);
                s = fmaf(Whh_[j * Hn + k], hf[k], s);
            }
            acc = fmaf(hn[j] * fsigmoid(s), Wfc[t * Hn + r0 + j], acc);
        }
    }

    // combine the two waves' partial FC sums
    if (wv == 0) sAcc[lane] = acc;
    __syncthreads();
    if (wv == 1) out[b] = acc + sAcc[lane];
}

extern "C" void kernel_launch(void* const* d_in, const int* in_sizes, int n_in,
                              void* d_out, int out_size, void* d_ws, size_t ws_size,
                              hipStream_t stream) {
    const float* r_emb   = (const float*)d_in[0];
    const float* feature = (const float*)d_in[1];
    const float* h0      = (const float*)d_in[2];
    const float* c0      = (const float*)d_in[3];
    const float* W_ih    = (const float*)d_in[4];
    const float* W_hh    = (const float*)d_in[5];
    const float* b_ih    = (const float*)d_in[6];
    const float* b_hh    = (const float*)d_in[7];
    const float* Wr      = (const float*)d_in[8];
    const float* br      = (const float*)d_in[9];
    const float* Wh      = (const float*)d_in[10];
    const float* bh      = (const float*)d_in[11];
    const float* Wfc     = (const float*)d_in[12];
    const float* bfc     = (const float*)d_in[13];
    float* out = (float*)d_out;

    dim3 grid(65536 / 64), block(128);
    hipLaunchKernelGGL(seqreader_kernel, grid, block, 0, stream,
                       r_emb, feature, h0, c0, W_ih, W_hh, b_ih, b_hh,
                       Wr, br, Wh, bh, Wfc, bfc, out);
}

// Round 4
// 210.785 us; speedup vs baseline: 3.8585x; 3.8585x over previous
//
#include <hip/hip_runtime.h>

#define Rn 64
#define Hn 10
#define Fn 5

__device__ __forceinline__ float fsigmoid(float x) {
    return __builtin_amdgcn_rcpf(1.0f + __expf(-x));
}
__device__ __forceinline__ float ftanh(float x) {
    return 1.0f - 2.0f * __builtin_amdgcn_rcpf(__expf(2.0f * x) + 1.0f);
}

// 2 lanes per batch, same wave: lane l (half 0) computes LSTM rows 0-4,
// lane l+32 (half 1) rows 5-9. h-halves exchanged via __shfl_xor(32) --
// no barrier, no LDS round-trip. 131072 threads = 2 waves/SIMD (round 2
// was 1/SIMD, 49% VALUBusy = latency-bound). Weights stay in LDS
// (broadcast per half-wave, 2 distinct addrs = free); x staged through
// double-buffered LDS tiles, 1 barrier per 4 steps.
__global__ __launch_bounds__(256, 2) void seqreader_kernel(
    const float* __restrict__ r_emb,
    const float* __restrict__ feature,
    const float* __restrict__ h0,
    const float* __restrict__ c0,
    const float* __restrict__ W_ih,
    const float* __restrict__ W_hh,
    const float* __restrict__ b_ih,
    const float* __restrict__ b_hh,
    const float* __restrict__ Wr,
    const float* __restrict__ br,
    const float* __restrict__ Wh,
    const float* __restrict__ bh,
    const float* __restrict__ Wfc,
    const float* __restrict__ bfc,
    float* __restrict__ out)
{
    __shared__ __align__(16) float sWih[40 * 12];
    __shared__ __align__(16) float sWhh[40 * 12];
    __shared__ __align__(16) float sWr[10 * 12];
    __shared__ __align__(16) float sWhn[10 * 12];
    __shared__ float sWfc[646];
    __shared__ float sX[2][128 * 41];  // [buf][batch][40 + pad]

    const int tid  = threadIdx.x;
    const int lane = tid & 63;
    const int half = lane >> 5;        // 0: rows 0-4, 1: rows 5-9
    const int r0h  = half * 5;
    const int bb   = (tid >> 6) * 32 + (lane & 31);  // batch within block, 0..127
    const int b0   = blockIdx.x * 128;
    const int b    = b0 + bb;

    // stage weights (padded row stride 12 -> ds_read_b128 groups)
    for (int i = tid; i < 400; i += 256) {
        int r = i / 10, k = i - r * 10;
        sWih[r * 12 + k] = W_ih[i];
        sWhh[r * 12 + k] = W_hh[i];
    }
    for (int i = tid; i < 100; i += 256) {
        int r = i / 10, k = i - r * 10;
        sWr[r * 12 + k]  = Wr[i];
        sWhn[r * 12 + k] = Wh[i];
    }
    for (int i = tid; i < 645; i += 256) sWfc[i] = Wfc[i];

    // per-lane-half biases (loaded once into VGPRs)
    float bi[5], bf_[5], bg_[5], bo[5], brh[5];
#pragma unroll
    for (int j = 0; j < 5; ++j) {
        bi[j]  = b_ih[0  + r0h + j] + b_hh[0  + r0h + j];
        bf_[j] = b_ih[10 + r0h + j] + b_hh[10 + r0h + j];
        bg_[j] = b_ih[20 + r0h + j] + b_hh[20 + r0h + j];
        bo[j]  = b_ih[30 + r0h + j] + b_hh[30 + r0h + j];
        brh[j] = br[r0h + j] + bh[r0h + j];
    }

    float c[5];
#pragma unroll
    for (int j = 0; j < 5; ++j) c[j] = c0[b * Hn + r0h + j];
    float hf[Hn];
#pragma unroll
    for (int k = 0; k < Hn; ++k) hf[k] = h0[b * Hn + k];

    float acc = 0.0f;
    if (half == 0) {
        acc = bfc[0];
#pragma unroll
        for (int k = 0; k < Fn; ++k)
            acc = fmaf(feature[b * Fn + k], Wfc[Rn * Hn + k], acc);
    }

    // gather map: tile = 128 batches x 40 floats = 1280 float4; 5 per thread
    unsigned off_g[5], off_l[5];
#pragma unroll
    for (int k = 0; k < 5; ++k) {
        int q  = k * 256 + tid;
        int bq = q / 10;
        int e  = q - bq * 10;
        off_g[k] = (unsigned)((bq * (Rn * Hn) + e * 4) * 4);  // bytes
        off_l[k] = (unsigned)(bq * 41 + e * 4);               // dwords
    }
    const char* gb = (const char*)(r_emb + (size_t)b0 * (Rn * Hn));

    // stage tile 0
    {
        float4 s0[5];
#pragma unroll
        for (int k = 0; k < 5; ++k) s0[k] = *(const float4*)(gb + off_g[k]);
#pragma unroll
        for (int k = 0; k < 5; ++k) {
            float* d = &sX[0][off_l[k]];
            d[0] = s0[k].x; d[1] = s0[k].y; d[2] = s0[k].z; d[3] = s0[k].w;
        }
    }
    __syncthreads();

    float4 st[5];
#pragma unroll 1
    for (int t = 0; t < Rn; ++t) {
        const int tt = t & 3;
        const int Tb = (t >> 2) & 1;

        if (tt == 0 && t + 4 < Rn) {
#pragma unroll
            for (int k = 0; k < 5; ++k)
                st[k] = *(const float4*)(gb + off_g[k] + (unsigned)(t / 4 + 1) * 160u);
        }

        float x[Hn];
        const float* xr = &sX[Tb][bb * 41 + tt * Hn];
#pragma unroll
        for (int j = 0; j < Hn; ++j) x[j] = xr[j];

        // own half of the LSTM cell (5 rows, all 4 gates)
        float hn[5];
#pragma unroll
        for (int j = 0; j < 5; ++j) {
            float si = bi[j], sf = bf_[j], sg = bg_[j], so = bo[j];
#pragma unroll
            for (int k = 0; k < Hn; ++k) {
                const float xk = x[k], hk = hf[k];
                si = fmaf(sWih[(0  + r0h + j) * 12 + k], xk, si);
                si = fmaf(sWhh[(0  + r0h + j) * 12 + k], hk, si);
                sf = fmaf(sWih[(10 + r0h + j) * 12 + k], xk, sf);
                sf = fmaf(sWhh[(10 + r0h + j) * 12 + k], hk, sf);
                sg = fmaf(sWih[(20 + r0h + j) * 12 + k], xk, sg);
                sg = fmaf(sWhh[(20 + r0h + j) * 12 + k], hk, sg);
                so = fmaf(sWih[(30 + r0h + j) * 12 + k], xk, so);
                so = fmaf(sWhh[(30 + r0h + j) * 12 + k], hk, so);
            }
            const float cn = fsigmoid(sf) * c[j] + fsigmoid(si) * ftanh(sg);
            c[j] = cn;
            hn[j] = fsigmoid(so) * ftanh(cn);
        }

        // exchange halves in-wave: partner lane = lane ^ 32
        float sw[5];
#pragma unroll
        for (int j = 0; j < 5; ++j) sw[j] = __shfl_xor(hn[j], 32, 64);
#pragma unroll
        for (int j = 0; j < 5; ++j) {
            hf[j]     = half ? sw[j] : hn[j];
            hf[5 + j] = half ? hn[j] : sw[j];
        }

        // write next x tile into the other buffer (prefetched at tt==0)
        if (tt == 2 && t + 2 < Rn) {
#pragma unroll
            for (int k = 0; k < 5; ++k) {
                float* d = &sX[Tb ^ 1][off_l[k]];
                d[0] = st[k].x; d[1] = st[k].y; d[2] = st[k].z; d[3] = st[k].w;
            }
        }

        // r-gate + fused FC accumulation (own rows)
#pragma unroll
        for (int j = 0; j < 5; ++j) {
            float s = brh[j];
#pragma unroll
            for (int k = 0; k < Hn; ++k) {
                s = fmaf(sWr[(r0h + j) * 12 + k], x[k], s);
                s = fmaf(sWhn[(r0h + j) * 12 + k], hf[k], s);
            }
            acc = fmaf(hn[j] * fsigmoid(s), sWfc[t * Hn + r0h + j], acc);
        }

        if (tt == 3) __syncthreads();
    }

    // combine the two lane-halves' partial FC sums; half 0 writes
    acc += __shfl_xor(acc, 32, 64);
    if (half == 0) out[b] = acc;
}

extern "C" void kernel_launch(void* const* d_in, const int* in_sizes, int n_in,
                              void* d_out, int out_size, void* d_ws, size_t ws_size,
                              hipStream_t stream) {
    const float* r_emb   = (const float*)d_in[0];
    const float* feature = (const float*)d_in[1];
    const float* h0      = (const float*)d_in[2];
    const float* c0      = (const float*)d_in[3];
    const float* W_ih    = (const float*)d_in[4];
    const float* W_hh    = (const float*)d_in[5];
    const float* b_ih    = (const float*)d_in[6];
    const float* b_hh    = (const float*)d_in[7];
    const float* Wr      = (const float*)d_in[8];
    const float* br      = (const float*)d_in[9];
    const float* Wh      = (const float*)d_in[10];
    const float* bh      = (const float*)d_in[11];
    const float* Wfc     = (const float*)d_in[12];
    const float* bfc     = (const float*)d_in[13];
    float* out = (float*)d_out;

    dim3 grid(65536 / 128), block(256);
    hipLaunchKernelGGL(seqreader_kernel, grid, block, 0, stream,
                       r_emb, feature, h0, c0, W_ih, W_hh, b_ih, b_hh,
                       Wr, br, Wh, bh, Wfc, bfc, out);
}